// Round 6
// baseline (414.949 us; speedup 1.0000x reference)
//
#include <hip/hip_runtime.h>
#include <cstdint>
#include <cstddef>

#define N_NODES 50000
#define E_EDGES 800000
#define IN_F    128
#define PCOLS   512   // P: [0,96) Y0 | [96,192) Zpre | [192,288) Zblk | [288,480) Zpost | pad

typedef unsigned short ushortT;
typedef unsigned int   uintT;
typedef __attribute__((ext_vector_type(8))) short s8v;   // 8 bf16 (4 VGPR)
typedef __attribute__((ext_vector_type(4))) float f4v;   // 4 fp32 acc

__device__ __forceinline__ float bflo(uintT u){ union{uintT i;float f;}c; c.i=u<<16; return c.f; }
__device__ __forceinline__ float bfhi(uintT u){ union{uintT i;float f;}c; c.i=u&0xFFFF0000u; return c.f; }
__device__ __forceinline__ ushortT f2bfu(float f){
    union{float f;uintT u;}c; c.f=f;
    uintT r = c.u + 0x7FFF + ((c.u>>16)&1);
    return (ushortT)(r>>16);
}
__device__ __forceinline__ uintT pack2(float a, float b){
    return (uintT)f2bfu(a) | ((uintT)f2bfu(b) << 16);
}

// ---------- pack weights: Wb [512][128] bf16 (gemm, transposed), bcat[512] fp32 ----------
__global__ void pack_weights(const float* __restrict__ Wp,  const float* __restrict__ bp,
                             const float* __restrict__ Tp,  const float* __restrict__ bTp,
                             const float* __restrict__ Tb,  const float* __restrict__ bTb,
                             const float* __restrict__ Tpo, const float* __restrict__ bTpo,
                             ushortT* __restrict__ Wb, float* __restrict__ bcat)
{
    int id = blockIdx.x * 256 + threadIdx.x;
    if (id >= IN_F * PCOLS) return;
    int k = id >> 9;
    int c = id & 511;
    float v;
    if      (c < 96)  v = Wp [k*96  + c];
    else if (c < 192) v = Tp [k*96  + (c-96)];
    else if (c < 288) v = Tb [k*96  + (c-192)];
    else if (c < 480) v = Tpo[k*192 + (c-288)];
    else              v = 0.f;
    Wb[(size_t)c*IN_F + k] = f2bfu(v);
    if (k == 0) {
        float b;
        if      (c < 96)  b = bp  [c];
        else if (c < 192) b = bTp [c-96];
        else if (c < 288) b = bTb [c-192];
        else if (c < 480) b = bTpo[c-288];
        else              b = 0.f;
        bcat[c] = b;
    }
}

// ---------- convert data fp32 -> Ab bf16 [N][128] ----------
__global__ void convert_data(const float* __restrict__ A, ushortT* __restrict__ Ab)
{
    int gid = blockIdx.x * 256 + threadIdx.x;
    size_t off = (size_t)gid * 8;
    float4 v0 = *(const float4*)(A + off);
    float4 v1 = *(const float4*)(A + off + 4);
    uint4 u;
    u.x = pack2(v0.x, v0.y); u.y = pack2(v0.z, v0.w);
    u.z = pack2(v1.x, v1.y); u.w = pack2(v1.z, v1.w);
    *(uint4*)(Ab + off) = u;
}

// ---------- row_ptr via binary search on sorted tgt ----------
__global__ void build_row_ptr(const int* __restrict__ tgt, int* __restrict__ row_ptr,
                              int E, int Np1)
{
    int t = blockIdx.x * 256 + threadIdx.x;
    if (t >= Np1) return;
    int lo = 0, hi = E;
    while (lo < hi) {
        int mid = (lo + hi) >> 1;
        if (tgt[mid] < t) lo = mid + 1; else hi = mid;
    }
    row_ptr[t] = lo;
}

// ---------- init padded index table (dummy = N_NODES) + zero rows of gather sources ----------
__global__ void init_pad(int* __restrict__ srcp,
                         ushortT* __restrict__ Y0b, ushortT* __restrict__ h1b,
                         ushortT* __restrict__ h2b)
{
    int gid = blockIdx.x * 256 + threadIdx.x;
    if (gid < N_NODES * 64) srcp[gid] = N_NODES;
    if (gid < 96)  Y0b[(size_t)N_NODES*96  + gid] = 0;
    if (gid < 96)  h1b[(size_t)N_NODES*96  + gid] = 0;
    if (gid < 192) h2b[(size_t)N_NODES*192 + gid] = 0;
}

// ---------- scatter first 64 edges of each node into srcp ----------
__global__ void fill_srcp(const int* __restrict__ src, const int* __restrict__ tgt,
                          const int* __restrict__ row_ptr, int* __restrict__ srcp)
{
    int e = blockIdx.x * 256 + threadIdx.x;
    if (e >= E_EDGES) return;
    int t = tgt[e];
    int slot = e - row_ptr[t];
    if (slot < 64) srcp[t*64 + slot] = src[e];
}

// ---------- MFMA GEMM: P[M,512] = Ab[M,128] @ Wb^T + bcat ; also emit Y0b bf16 ----------
__global__ __launch_bounds__(256, 2) void gemm_mfma(const ushortT* __restrict__ Ab,
                                                    const ushortT* __restrict__ Wb,
                                                    const float* __restrict__ bcat,
                                                    float* __restrict__ P,
                                                    ushortT* __restrict__ Y0b, int M)
{
    __shared__ ushortT Asl[128][72];
    __shared__ ushortT Bsl[128][72];
    int tid = threadIdx.x;
    int nb = blockIdx.x * 128;
    int mb = blockIdx.y * 128;
    int wv = tid >> 6, lane = tid & 63;
    int wm = wv >> 1, wn = wv & 1;
    int cl = lane & 15, q = lane >> 4;

    f4v acc[4][4];
    #pragma unroll
    for (int i = 0; i < 4; ++i)
        #pragma unroll
        for (int j = 0; j < 4; ++j) acc[i][j] = (f4v)0.f;

    for (int kt = 0; kt < IN_F; kt += 64) {
        if (kt) __syncthreads();
        #pragma unroll
        for (int r = 0; r < 4; ++r) {
            int idx = tid + 256*r;
            int row = idx >> 3, qq = idx & 7;
            int gm = mb + row;
            uint4 v = make_uint4(0,0,0,0);
            if (gm < M) v = *(const uint4*)(Ab + (size_t)gm*IN_F + kt + qq*8);
            *(uint4*)(&Asl[row][qq*8]) = v;
        }
        #pragma unroll
        for (int r = 0; r < 4; ++r) {
            int idx = tid + 256*r;
            int row = idx >> 3, qq = idx & 7;
            uint4 v = *(const uint4*)(Wb + (size_t)(nb+row)*IN_F + kt + qq*8);
            *(uint4*)(&Bsl[row][qq*8]) = v;
        }
        __syncthreads();
        #pragma unroll
        for (int ks = 0; ks < 2; ++ks) {
            int ko = ks*32 + q*8;
            s8v af[4], bf[4];
            #pragma unroll
            for (int mt = 0; mt < 4; ++mt)
                af[mt] = *(const s8v*)(&Asl[wm*64 + mt*16 + cl][ko]);
            #pragma unroll
            for (int nt = 0; nt < 4; ++nt)
                bf[nt] = *(const s8v*)(&Bsl[wn*64 + nt*16 + cl][ko]);
            #pragma unroll
            for (int mt = 0; mt < 4; ++mt)
                #pragma unroll
                for (int nt = 0; nt < 4; ++nt)
                    acc[mt][nt] = __builtin_amdgcn_mfma_f32_16x16x32_bf16(af[mt], bf[nt], acc[mt][nt], 0, 0, 0);
        }
    }

    bool y0blk = (nb == 0) && (wn == 0);
    #pragma unroll
    for (int nt = 0; nt < 4; ++nt) {
        int gn = nb + wn*64 + nt*16 + cl;
        float bv = bcat[gn];
        bool doY = y0blk && (gn < 96);
        #pragma unroll
        for (int mt = 0; mt < 4; ++mt) {
            int gm0 = mb + wm*64 + mt*16 + q*4;
            #pragma unroll
            for (int r = 0; r < 4; ++r) {
                int gm = gm0 + r;
                if (gm < M) {
                    float val = acc[mt][nt][r] + bv;
                    P[(size_t)gm*PCOLS + gn] = val;
                    if (doY) Y0b[(size_t)gm*96 + gn] = f2bfu(val);
                }
            }
        }
    }
}

// ---------- lap96: ro[t] = relu(Lap(Xb)[t] + Z[t])  fp32 out, wave per node ----------
__global__ __launch_bounds__(256) void lap96(
    const ushortT* __restrict__ Xb,    // [N+1,96] bf16, zero row at N
    const float*   __restrict__ Pown,  // fp32 own-x rows ([N,512], cols 0..95) or null
    const float*   __restrict__ Z,     // [N,512] + col offset applied
    const int* __restrict__ srcp,      // [N,64] padded indices
    const int* __restrict__ src, const int* __restrict__ row_ptr,
    float* __restrict__ ro)            // [N,96] fp32
{
    int lane = threadIdx.x & 63;
    int t  = __builtin_amdgcn_readfirstlane((blockIdx.x << 2) + (threadIdx.x >> 6));
    int lo = __builtin_amdgcn_readfirstlane(row_ptr[t]);
    int hi = __builtin_amdgcn_readfirstlane(row_ptr[t+1]);
    int deg = hi - lo;
    int pL = lane < 48 ? lane : 0;

    int sv = srcp[t*64 + lane];
    // hoisted own-x and Z
    float xx, xy;
    if (Pown) {
        float2 xr = *(const float2*)(Pown + (size_t)t*PCOLS + 2*pL);
        xx = xr.x; xy = xr.y;
    } else {
        uintT ux = *(const uintT*)(Xb + (size_t)t*96 + 2*pL);
        xx = bflo(ux); xy = bfhi(ux);
    }
    float2 zr = *(const float2*)(Z + (size_t)t*PCOLS + 2*pL);

    float c0x=0.f,c0y=0.f,c1x=0.f,c1y=0.f,c2x=0.f,c2y=0.f,c3x=0.f,c3y=0.f;
    int dmax = deg < 64 ? deg : 64;
    #pragma unroll 1
    for (int w = 0; w < dmax; w += 16) {
        uintT u[16];
        #pragma unroll
        for (int kk = 0; kk < 16; ++kk) {
            int idx = __builtin_amdgcn_readlane(sv, w + kk);   // dummy slots -> N (zero row)
            u[kk] = *(const uintT*)(Xb + (size_t)idx*96 + 2*pL);
        }
        #pragma unroll
        for (int kk = 0; kk < 16; ++kk) {
            float lo_ = bflo(u[kk]), hi_ = bfhi(u[kk]);
            switch (kk & 3) {
                case 0: c0x += lo_; c0y += hi_; break;
                case 1: c1x += lo_; c1y += hi_; break;
                case 2: c2x += lo_; c2y += hi_; break;
                default:c3x += lo_; c3y += hi_; break;
            }
        }
    }
    if (deg > 64) {     // rare/never fallback
        #pragma unroll 1
        for (int j = lo + 64; j < hi; ++j) {
            int idx = src[j];
            uintT u0 = *(const uintT*)(Xb + (size_t)idx*96 + 2*pL);
            c0x += bflo(u0); c0y += bfhi(u0);
        }
    }
    float sx = (c0x+c1x)+(c2x+c3x);
    float sy = (c0y+c1y)+(c2y+c3y);
    float inv = deg > 0 ? 1.f/(float)deg : 0.f;
    float mf  = deg > 0 ? 1.f : 0.f;
    if (lane < 48) {
        float2 o;
        o.x = fmaxf(mf*xx - sx*inv + zr.x, 0.f);
        o.y = fmaxf(mf*xy - sy*inv + zr.y, 0.f);
        *(float2*)(ro + (size_t)t*96 + 2*pL) = o;
    }
}

// ---------- grouped 1x1 conv: fp32 in -> bf16 out ----------
template<int HO>
__global__ __launch_bounds__(256) void grouped_conv(
    const float* __restrict__ X,   // [N,96] fp32
    const float* __restrict__ Wg,  // [3,32,HO] flat
    const float* __restrict__ bg,  // [3,HO]
    ushortT* __restrict__ outb)    // [N+1, 3*HO] bf16 (zero row preserved)
{
    __shared__ float wS[3*32*HO];
    __shared__ float bS[3*HO];
    for (int i = threadIdx.x; i < 3*32*HO; i += 256) wS[i] = Wg[i];
    for (int i = threadIdx.x; i < 3*HO;    i += 256) bS[i] = bg[i];
    __syncthreads();
    int gid = blockIdx.x * 256 + threadIdx.x;
    int t = gid / (3*HO);
    int c = gid - t*(3*HO);
    if (t >= N_NODES) return;
    int w = c / HO, j = c - w*HO;
    const float* xr = X + (size_t)t*96 + w*32;
    const float* wp = &wS[(w*32)*HO + j];
    float s = bS[c];
    #pragma unroll
    for (int i = 0; i < 32; ++i) s = fmaf(xr[i], wp[i*HO], s);
    outb[(size_t)t*(3*HO) + c] = f2bfu(s);
}

// ---------- final: relu(Lap(h2b)+Zpost), width-mean via shfl -> out[N,64] ----------
__global__ __launch_bounds__(256) void lap_final(
    const ushortT* __restrict__ Xb,   // [N+1,192] bf16, zero row at N
    const float* __restrict__ Z,      // P + 288
    const int* __restrict__ srcp, const int* __restrict__ src,
    const int* __restrict__ row_ptr,
    float* __restrict__ out)
{
    int lane = threadIdx.x & 63;
    int t  = __builtin_amdgcn_readfirstlane((blockIdx.x << 2) + (threadIdx.x >> 6));
    int lo = __builtin_amdgcn_readfirstlane(row_ptr[t]);
    int hi = __builtin_amdgcn_readfirstlane(row_ptr[t+1]);
    int deg = hi - lo;
    int pL2 = lane & 31;

    int sv = srcp[t*64 + lane];
    uintT uxa = *(const uintT*)(Xb + (size_t)t*192 + 2*lane);
    uintT uxb = *(const uintT*)(Xb + (size_t)t*192 + 128 + 2*pL2);
    float2 za  = *(const float2*)(Z + (size_t)t*PCOLS + 2*lane);
    float2 zb  = *(const float2*)(Z + (size_t)t*PCOLS + 128 + 2*pL2);

    float a0x=0,a0y=0,a1x=0,a1y=0;   // feats 2L,2L+1 (two chains)
    float b0x=0,b0y=0,b1x=0,b1y=0;   // feats 128+2L'
    int dmax = deg < 64 ? deg : 64;
    #pragma unroll 1
    for (int w = 0; w < dmax; w += 8) {
        uintT ua[8], ub[8];
        #pragma unroll
        for (int kk = 0; kk < 8; ++kk) {
            int idx = __builtin_amdgcn_readlane(sv, w + kk);
            const ushortT* rp = Xb + (size_t)idx*192;
            ua[kk] = *(const uintT*)(rp + 2*lane);
            ub[kk] = *(const uintT*)(rp + 128 + 2*pL2);
        }
        #pragma unroll
        for (int kk = 0; kk < 8; ++kk) {
            if (kk & 1) {
                a1x += bflo(ua[kk]); a1y += bfhi(ua[kk]);
                b1x += bflo(ub[kk]); b1y += bfhi(ub[kk]);
            } else {
                a0x += bflo(ua[kk]); a0y += bfhi(ua[kk]);
                b0x += bflo(ub[kk]); b0y += bfhi(ub[kk]);
            }
        }
    }
    if (deg > 64) {
        #pragma unroll 1
        for (int j = lo + 64; j < hi; ++j) {
            int idx = src[j];
            const ushortT* rp = Xb + (size_t)idx*192;
            uintT ua0 = *(const uintT*)(rp + 2*lane);
            uintT ub0 = *(const uintT*)(rp + 128 + 2*pL2);
            a0x += bflo(ua0); a0y += bfhi(ua0);
            b0x += bflo(ub0); b0y += bfhi(ub0);
        }
    }
    float sax = a0x + a1x, say = a0y + a1y;
    float sbx = b0x + b1x, sby = b0y + b1y;
    float inv = deg > 0 ? 1.f/(float)deg : 0.f;
    float mf  = deg > 0 ? 1.f : 0.f;
    float2 oa, ob;
    oa.x = fmaxf(mf*bflo(uxa) - sax*inv + za.x, 0.f);
    oa.y = fmaxf(mf*bfhi(uxa) - say*inv + za.y, 0.f);
    ob.x = fmaxf(mf*bflo(uxb) - sbx*inv + zb.x, 0.f);
    ob.y = fmaxf(mf*bfhi(uxb) - sby*inv + zb.y, 0.f);
    float r = 0.f;
    #pragma unroll
    for (int qq = 0; qq < 3; ++qq) {
        int g  = 3*lane + qq;
        int pa = (g >> 1) & 63;
        int pb = ((g - 128) >> 1) & 63;
        float cax = __shfl(oa.x, pa), cay = __shfl(oa.y, pa);
        float cbx = __shfl(ob.x, pb), cby = __shfl(ob.y, pb);
        float v = (g < 128) ? ((g & 1) ? cay : cax)
                            : ((g & 1) ? cby : cbx);
        r += v;
    }
    out[(size_t)t*64 + lane] = r * (1.0f/3.0f);
}

extern "C" void kernel_launch(void* const* d_in, const int* in_sizes, int n_in,
                              void* d_out, int out_size, void* d_ws, size_t ws_size,
                              hipStream_t stream)
{
    const float* data    = (const float*)d_in[0];
    const int*   src     = (const int*)  d_in[1];
    const int*   tgt     = (const int*)  d_in[2];
    const float* W_pre   = (const float*)d_in[3];
    const float* b_pre   = (const float*)d_in[4];
    const float* T_pre   = (const float*)d_in[5];
    const float* bT_pre  = (const float*)d_in[6];
    const float* W_blk   = (const float*)d_in[7];
    const float* b_blk   = (const float*)d_in[8];
    const float* T_blk   = (const float*)d_in[9];
    const float* bT_blk  = (const float*)d_in[10];
    const float* W_post  = (const float*)d_in[11];
    const float* b_post  = (const float*)d_in[12];
    const float* T_post  = (const float*)d_in[13];
    const float* bT_post = (const float*)d_in[14];
    float* out = (float*)d_out;

    float* ws = (float*)d_ws;
    float*   P       = ws;                                   // N*512 f32
    float*   bcat    = P + (size_t)N_NODES * PCOLS;          // 512
    float*   ro      = bcat + 512;                           // N*96 f32 (reused both layers)
    int*     row_ptr = (int*)(ro + (size_t)N_NODES * 96);    // 50008
    int*     srcp    = row_ptr + 50008;                      // N*64
    ushortT* Y0b     = (ushortT*)(srcp + (size_t)N_NODES*64);   // (N+1)*96 bf16
    ushortT* h1b     = Y0b + (size_t)(N_NODES+1) * 96;          // (N+1)*96 bf16
    ushortT* h2b     = h1b + (size_t)(N_NODES+1) * 96;          // (N+1)*192 bf16
    ushortT* Ab      = h2b + (size_t)(N_NODES+1) * 192;         // N*128 bf16
    ushortT* Wb      = Ab  + (size_t)N_NODES * IN_F;            // 512*128 bf16

    pack_weights<<<(IN_F*PCOLS + 255)/256, 256, 0, stream>>>(
        W_pre, b_pre, T_pre, bT_pre, T_blk, bT_blk, T_post, bT_post, Wb, bcat);

    convert_data<<<(N_NODES*IN_F/8 + 255)/256, 256, 0, stream>>>(data, Ab);

    build_row_ptr<<<(N_NODES + 1 + 255)/256, 256, 0, stream>>>(tgt, row_ptr, E_EDGES, N_NODES + 1);

    init_pad<<<(N_NODES*64 + 255)/256, 256, 0, stream>>>(srcp, Y0b, h1b, h2b);

    fill_srcp<<<(E_EDGES + 255)/256, 256, 0, stream>>>(src, tgt, row_ptr, srcp);

    dim3 gg(PCOLS/128, (N_NODES + 127)/128);
    gemm_mfma<<<gg, 256, 0, stream>>>(Ab, Wb, bcat, P, Y0b, N_NODES);

    // layer 1: ro = relu(Lap(Y0)+Zpre); conv_blk -> h1b
    lap96<<<(N_NODES + 3)/4, 256, 0, stream>>>(Y0b, P, P + 96, srcp, src, row_ptr, ro);
    grouped_conv<32><<<(N_NODES*96 + 255)/256, 256, 0, stream>>>(ro, W_blk, b_blk, h1b);
    // layer 2: ro = relu(Lap(h1)+Zblk); conv_post -> h2b
    lap96<<<(N_NODES + 3)/4, 256, 0, stream>>>(h1b, nullptr, P + 192, srcp, src, row_ptr, ro);
    grouped_conv<64><<<(N_NODES*192 + 255)/256, 256, 0, stream>>>(ro, W_post, b_post, h2b);
    // layer 3 + width-mean
    lap_final<<<(N_NODES + 3)/4, 256, 0, stream>>>(h2b, P + 288, srcp, src, row_ptr, out);
}

// Round 7
// 303.412 us; speedup vs baseline: 1.3676x; 1.3676x over previous
//
#include <hip/hip_runtime.h>
#include <cstdint>
#include <cstddef>

#define N_NODES 50000
#define E_EDGES 800000
#define IN_F    128
#define PCOLS   512   // P: [0,96) Y0 | [96,192) Zpre | [192,288) Zblk | [288,480) Zpost | pad

typedef unsigned short ushortT;
typedef unsigned int   uintT;
typedef __attribute__((ext_vector_type(8))) short s8v;   // 8 bf16 (4 VGPR)
typedef __attribute__((ext_vector_type(4))) float f4v;   // 4 fp32 acc

__device__ __forceinline__ float bflo(uintT u){ union{uintT i;float f;}c; c.i=u<<16; return c.f; }
__device__ __forceinline__ float bfhi(uintT u){ union{uintT i;float f;}c; c.i=u&0xFFFF0000u; return c.f; }
__device__ __forceinline__ ushortT f2bfu(float f){
    union{float f;uintT u;}c; c.f=f;
    uintT r = c.u + 0x7FFF + ((c.u>>16)&1);
    return (ushortT)(r>>16);
}
__device__ __forceinline__ uintT pack2(float a, float b){
    return (uintT)f2bfu(a) | ((uintT)f2bfu(b) << 16);
}
__device__ __forceinline__ float rdlanef(float v, int sl){
    return __int_as_float(__builtin_amdgcn_readlane(__float_as_int(v), sl));
}

// ---------- pack weights: Wb [512][128] bf16, bcat[512] fp32, Wp2 [3][16][64] float2 ----------
__global__ void pack_weights(const float* __restrict__ Wp,  const float* __restrict__ bp,
                             const float* __restrict__ Tp,  const float* __restrict__ bTp,
                             const float* __restrict__ Tb,  const float* __restrict__ bTb,
                             const float* __restrict__ Tpo, const float* __restrict__ bTpo,
                             const float* __restrict__ Wpost,
                             ushortT* __restrict__ Wb, float* __restrict__ bcat,
                             float2* __restrict__ Wp2)
{
    int id = blockIdx.x * 256 + threadIdx.x;
    if (id >= IN_F * PCOLS) return;
    int k = id >> 9;
    int c = id & 511;
    float v;
    if      (c < 96)  v = Wp [k*96  + c];
    else if (c < 192) v = Tp [k*96  + (c-96)];
    else if (c < 288) v = Tb [k*96  + (c-192)];
    else if (c < 480) v = Tpo[k*192 + (c-288)];
    else              v = 0.f;
    Wb[(size_t)c*IN_F + k] = f2bfu(v);
    if (k == 0) {
        float b;
        if      (c < 96)  b = bp  [c];
        else if (c < 192) b = bTp [c-96];
        else if (c < 288) b = bTb [c-192];
        else if (c < 480) b = bTpo[c-288];
        else              b = 0.f;
        bcat[c] = b;
    }
    if (id < 3*16*64) {   // Wp2[(w*16+i2)*64+j] = (Wpost[w][2i2][j], Wpost[w][2i2+1][j])
        int w = id >> 10, r = id & 1023;
        int i2 = r >> 6, j = r & 63;
        Wp2[id] = make_float2(Wpost[(w*32 + 2*i2)*64 + j],
                              Wpost[(w*32 + 2*i2 + 1)*64 + j]);
    }
}

// ---------- convert data fp32 -> Ab bf16 [N][128] ----------
__global__ void convert_data(const float* __restrict__ A, ushortT* __restrict__ Ab)
{
    int gid = blockIdx.x * 256 + threadIdx.x;
    size_t off = (size_t)gid * 8;
    float4 v0 = *(const float4*)(A + off);
    float4 v1 = *(const float4*)(A + off + 4);
    uint4 u;
    u.x = pack2(v0.x, v0.y); u.y = pack2(v0.z, v0.w);
    u.z = pack2(v1.x, v1.y); u.w = pack2(v1.z, v1.w);
    *(uint4*)(Ab + off) = u;
}

// ---------- row_ptr via binary search on sorted tgt ----------
__global__ void build_row_ptr(const int* __restrict__ tgt, int* __restrict__ row_ptr,
                              int E, int Np1)
{
    int t = blockIdx.x * 256 + threadIdx.x;
    if (t >= Np1) return;
    int lo = 0, hi = E;
    while (lo < hi) {
        int mid = (lo + hi) >> 1;
        if (tgt[mid] < t) lo = mid + 1; else hi = mid;
    }
    row_ptr[t] = lo;
}

// ---------- srcp[t][slot] = slot<deg ? src[lo+slot] : N ; zero rows of gather sources ----------
__global__ void build_srcp(const int* __restrict__ src, const int* __restrict__ row_ptr,
                           int* __restrict__ srcp,
                           ushortT* __restrict__ Y0b, ushortT* __restrict__ rb1,
                           ushortT* __restrict__ rb2)
{
    int gid = blockIdx.x * 256 + threadIdx.x;   // N*64 threads
    int t = gid >> 6, slot = gid & 63;
    int lo = row_ptr[t];
    int deg = row_ptr[t+1] - lo;
    srcp[gid] = slot < deg ? src[lo + slot] : N_NODES;
    if (gid < 96) {
        Y0b[(size_t)N_NODES*96 + gid] = 0;
        rb1[(size_t)N_NODES*96 + gid] = 0;
        rb2[(size_t)N_NODES*96 + gid] = 0;
    }
}

// ---------- MFMA GEMM: P[M,512] = Ab[M,128] @ Wb^T + bcat ; also emit Y0b bf16 ----------
__global__ __launch_bounds__(256, 2) void gemm_mfma(const ushortT* __restrict__ Ab,
                                                    const ushortT* __restrict__ Wb,
                                                    const float* __restrict__ bcat,
                                                    float* __restrict__ P,
                                                    ushortT* __restrict__ Y0b, int M)
{
    __shared__ ushortT Asl[128][72];
    __shared__ ushortT Bsl[128][72];
    int tid = threadIdx.x;
    int nb = blockIdx.x * 128;
    int mb = blockIdx.y * 128;
    int wv = tid >> 6, lane = tid & 63;
    int wm = wv >> 1, wn = wv & 1;
    int cl = lane & 15, q = lane >> 4;

    f4v acc[4][4];
    #pragma unroll
    for (int i = 0; i < 4; ++i)
        #pragma unroll
        for (int j = 0; j < 4; ++j) acc[i][j] = (f4v)0.f;

    for (int kt = 0; kt < IN_F; kt += 64) {
        if (kt) __syncthreads();
        #pragma unroll
        for (int r = 0; r < 4; ++r) {
            int idx = tid + 256*r;
            int row = idx >> 3, qq = idx & 7;
            int gm = mb + row;
            uint4 v = make_uint4(0,0,0,0);
            if (gm < M) v = *(const uint4*)(Ab + (size_t)gm*IN_F + kt + qq*8);
            *(uint4*)(&Asl[row][qq*8]) = v;
        }
        #pragma unroll
        for (int r = 0; r < 4; ++r) {
            int idx = tid + 256*r;
            int row = idx >> 3, qq = idx & 7;
            uint4 v = *(const uint4*)(Wb + (size_t)(nb+row)*IN_F + kt + qq*8);
            *(uint4*)(&Bsl[row][qq*8]) = v;
        }
        __syncthreads();
        #pragma unroll
        for (int ks = 0; ks < 2; ++ks) {
            int ko = ks*32 + q*8;
            s8v af[4], bf[4];
            #pragma unroll
            for (int mt = 0; mt < 4; ++mt)
                af[mt] = *(const s8v*)(&Asl[wm*64 + mt*16 + cl][ko]);
            #pragma unroll
            for (int nt = 0; nt < 4; ++nt)
                bf[nt] = *(const s8v*)(&Bsl[wn*64 + nt*16 + cl][ko]);
            #pragma unroll
            for (int mt = 0; mt < 4; ++mt)
                #pragma unroll
                for (int nt = 0; nt < 4; ++nt)
                    acc[mt][nt] = __builtin_amdgcn_mfma_f32_16x16x32_bf16(af[mt], bf[nt], acc[mt][nt], 0, 0, 0);
        }
    }

    bool y0blk = (nb == 0) && (wn == 0);
    #pragma unroll
    for (int nt = 0; nt < 4; ++nt) {
        int gn = nb + wn*64 + nt*16 + cl;
        float bv = bcat[gn];
        bool doY = y0blk && (gn < 96);
        #pragma unroll
        for (int mt = 0; mt < 4; ++mt) {
            int gm0 = mb + wm*64 + mt*16 + q*4;
            #pragma unroll
            for (int r = 0; r < 4; ++r) {
                int gm = gm0 + r;
                if (gm < M) {
                    float val = acc[mt][nt][r] + bv;
                    P[(size_t)gm*PCOLS + gn] = val;
                    if (doY) Y0b[(size_t)gm*96 + gn] = f2bfu(val);
                }
            }
        }
    }
}

// ===== shared gather core: sum of Xb rows per srcp window (96 bf16 feats) =====
// Returns sx (feat 2pL), sy (feat 2pL+1). deg, lo precomputed.
#define GATHER96(Xb, t, lo, hi, deg, sv, pL, sx, sy)                              \
    float sx, sy;                                                                 \
    {                                                                             \
        float c0x=0.f,c0y=0.f,c1x=0.f,c1y=0.f,c2x=0.f,c2y=0.f,c3x=0.f,c3y=0.f;    \
        int dmax = deg < 64 ? deg : 64;                                           \
        _Pragma("unroll 1")                                                       \
        for (int w_ = 0; w_ < dmax; w_ += 16) {                                   \
            uintT u[16];                                                          \
            _Pragma("unroll")                                                     \
            for (int kk = 0; kk < 16; ++kk) {                                     \
                int idx = __builtin_amdgcn_readlane(sv, w_ + kk);                 \
                u[kk] = *(const uintT*)(Xb + (size_t)idx*96 + 2*pL);              \
            }                                                                     \
            _Pragma("unroll")                                                     \
            for (int kk = 0; kk < 16; ++kk) {                                     \
                float lo_ = bflo(u[kk]), hi_ = bfhi(u[kk]);                       \
                switch (kk & 3) {                                                 \
                    case 0: c0x += lo_; c0y += hi_; break;                        \
                    case 1: c1x += lo_; c1y += hi_; break;                        \
                    case 2: c2x += lo_; c2y += hi_; break;                        \
                    default:c3x += lo_; c3y += hi_; break;                        \
                }                                                                 \
            }                                                                     \
        }                                                                         \
        if (deg > 64) {                                                           \
            _Pragma("unroll 1")                                                   \
            for (int j_ = lo + 64; j_ < lo + deg; ++j_) {                         \
                int idx = src[j_];                                                \
                uintT u0 = *(const uintT*)(Xb + (size_t)idx*96 + 2*pL);           \
                c0x += bflo(u0); c0y += bfhi(u0);                                 \
            }                                                                     \
        }                                                                         \
        sx = (c0x+c1x)+(c2x+c3x);                                                 \
        sy = (c0y+c1y)+(c2y+c3y);                                                 \
    }

// ---------- layer 1: rb1 = bf16(relu(Lap(Y0) + Zpre)), wave per node ----------
__global__ __launch_bounds__(256) void lap1(
    const ushortT* __restrict__ Xb,    // Y0b [N+1,96]
    const float*   __restrict__ Pown,  // P (cols 0..95 fp32 own-x)
    const float*   __restrict__ Z,     // P + 96
    const int* __restrict__ srcp, const int* __restrict__ src,
    const int* __restrict__ row_ptr,
    ushortT* __restrict__ rb1)
{
    int lane = threadIdx.x & 63;
    int t  = __builtin_amdgcn_readfirstlane((blockIdx.x << 2) + (threadIdx.x >> 6));
    int lo = __builtin_amdgcn_readfirstlane(row_ptr[t]);
    int deg = __builtin_amdgcn_readfirstlane(row_ptr[t+1]) - lo;
    int pL = lane < 48 ? lane : 0;
    int sv = srcp[t*64 + lane];
    float2 xr = *(const float2*)(Pown + (size_t)t*PCOLS + 2*pL);
    float2 zr = *(const float2*)(Z    + (size_t)t*PCOLS + 2*pL);

    GATHER96(Xb, t, lo, lo+deg, deg, sv, pL, sx, sy)

    float inv = deg > 0 ? 1.f/(float)deg : 0.f;
    float mf  = deg > 0 ? 1.f : 0.f;
    if (lane < 48) {
        float ox = fmaxf(mf*xr.x - sx*inv + zr.x, 0.f);
        float oy = fmaxf(mf*xr.y - sy*inv + zr.y, 0.f);
        *(uintT*)(rb1 + (size_t)t*96 + 2*pL) = pack2(ox, oy);
    }
}

// ---------- layer 2: rb2 = bf16(relu(Lap(rb1)@W_blk + Zblk))  [conv commuted past Lap] ----------
#define CPB 20
__global__ __launch_bounds__(256) void lap2(
    const ushortT* __restrict__ Xb,    // rb1 [N+1,96]
    const float*   __restrict__ Z,     // P + 192 (Zblk)
    const int* __restrict__ srcp, const int* __restrict__ src,
    const int* __restrict__ row_ptr,
    const float* __restrict__ Wblk,    // [3][32][32] flat
    ushortT* __restrict__ rb2)
{
    __shared__ float wS[3*32*32];
    for (int i = threadIdx.x; i < 3072; i += 256) wS[i] = Wblk[i];
    __syncthreads();

    int lane = threadIdx.x & 63;
    int wvw  = threadIdx.x >> 6;
    int pL = lane < 48 ? lane : 0;
    int w  = pL >> 4;            // group (uniform per 16-lane slab)
    int jj = pL & 15;            // out pair index within group
    const float2* wc = ((const float2*)wS) + (w*512 + jj);   // &W[w][0][2jj]

    #pragma unroll 1
    for (int trip = 0; trip < CPB/4; ++trip) {
        int t  = __builtin_amdgcn_readfirstlane(blockIdx.x*CPB + 4*trip + wvw);
        int lo = __builtin_amdgcn_readfirstlane(row_ptr[t]);
        int deg = __builtin_amdgcn_readfirstlane(row_ptr[t+1]) - lo;
        int sv = srcp[t*64 + lane];
        uintT ux = *(const uintT*)(Xb + (size_t)t*96 + 2*pL);
        float2 zr = *(const float2*)(Z + (size_t)t*PCOLS + 2*pL);

        GATHER96(Xb, t, lo, lo+deg, deg, sv, pL, sx, sy)

        float inv = deg > 0 ? 1.f/(float)deg : 0.f;
        float mf  = deg > 0 ? 1.f : 0.f;
        float Lx = mf*bflo(ux) - sx*inv;    // Lap feat 2pL
        float Ly = mf*bfhi(ux) - sy*inv;    // Lap feat 2pL+1

        // conv (no bias): out channels (2pL, 2pL+1), inputs = group-w feats via shfl
        float accx = 0.f, accy = 0.f;
        #pragma unroll
        for (int d = 0; d < 16; ++d) {
            int sl = w*16 + d;
            float ax = __shfl(Lx, sl);      // feat 32w+2d
            float ay = __shfl(Ly, sl);      // feat 32w+2d+1
            float2 wa = wc[(2*d)*16];       // W[w][2d][2jj..2jj+1]
            float2 wb = wc[(2*d+1)*16];
            accx = fmaf(ax, wa.x, accx); accx = fmaf(ay, wb.x, accx);
            accy = fmaf(ax, wa.y, accy); accy = fmaf(ay, wb.y, accy);
        }
        if (lane < 48) {
            float ox = fmaxf(accx + zr.x, 0.f);
            float oy = fmaxf(accy + zr.y, 0.f);
            *(uintT*)(rb2 + (size_t)t*96 + 2*pL) = pack2(ox, oy);
        }
    }
}

// ---------- layer 3: out = widthmean(relu(Lap(rb2)@W_post + Zpost)) ----------
__global__ __launch_bounds__(256) void lap3(
    const ushortT* __restrict__ Xb,    // rb2 [N+1,96]
    const float*   __restrict__ Z,     // P + 288 (Zpost)
    const int* __restrict__ srcp, const int* __restrict__ src,
    const int* __restrict__ row_ptr,
    const float2* __restrict__ Wp2,    // [3][16][64] float2
    float* __restrict__ out)
{
    __shared__ float2 wS[3*16*64];
    for (int i = threadIdx.x; i < 3072; i += 256) wS[i] = Wp2[i];
    __syncthreads();

    int lane = threadIdx.x & 63;
    int wvw  = threadIdx.x >> 6;
    int pL = lane < 48 ? lane : 0;
    const float2* wl = wS + lane;      // step 64 float2 per (w,i2)

    #pragma unroll 1
    for (int trip = 0; trip < CPB/4; ++trip) {
        int t  = __builtin_amdgcn_readfirstlane(blockIdx.x*CPB + 4*trip + wvw);
        int lo = __builtin_amdgcn_readfirstlane(row_ptr[t]);
        int deg = __builtin_amdgcn_readfirstlane(row_ptr[t+1]) - lo;
        int sv = srcp[t*64 + lane];
        uintT ux = *(const uintT*)(Xb + (size_t)t*96 + 2*pL);
        float z0 = Z[(size_t)t*PCOLS + lane];
        float z1 = Z[(size_t)t*PCOLS + 64 + lane];
        float z2 = Z[(size_t)t*PCOLS + 128 + lane];

        GATHER96(Xb, t, lo, lo+deg, deg, sv, pL, sx, sy)

        float inv = deg > 0 ? 1.f/(float)deg : 0.f;
        float mf  = deg > 0 ? 1.f : 0.f;
        float Lx = mf*bflo(ux) - sx*inv;
        float Ly = mf*bfhi(ux) - sy*inv;

        // conv: lane computes channels {L, 64+L, 128+L}; acts broadcast via readlane
        float a0 = 0.f, a1 = 0.f, a2 = 0.f;
        #pragma unroll
        for (int w2 = 0; w2 < 3; ++w2) {
            float acc = 0.f;
            #pragma unroll
            for (int i2 = 0; i2 < 16; ++i2) {
                float ax = rdlanef(Lx, 16*w2 + i2);   // feat 32w2+2i2
                float ay = rdlanef(Ly, 16*w2 + i2);   // feat 32w2+2i2+1
                float2 p = wl[(w2*16 + i2)*64];
                acc = fmaf(ax, p.x, acc);
                acc = fmaf(ay, p.y, acc);
            }
            if (w2 == 0) a0 = acc; else if (w2 == 1) a1 = acc; else a2 = acc;
        }
        float o0 = fmaxf(a0 + z0, 0.f);   // channel lane
        float o1 = fmaxf(a1 + z1, 0.f);   // channel 64+lane
        float o2 = fmaxf(a2 + z2, 0.f);   // channel 128+lane
        // width-mean: final[f] = (v(3f)+v(3f+1)+v(3f+2))/3, v(c) = o_{c>>6} @ lane c&63
        float r = 0.f;
        #pragma unroll
        for (int q = 0; q < 3; ++q) {
            int c = 3*lane + q;
            int sl = c & 63, wsel = c >> 6;
            float v0 = __shfl(o0, sl);
            float v1 = __shfl(o1, sl);
            float v2 = __shfl(o2, sl);
            r += (wsel == 0) ? v0 : ((wsel == 1) ? v1 : v2);
        }
        out[(size_t)t*64 + lane] = r * (1.0f/3.0f);
    }
}

extern "C" void kernel_launch(void* const* d_in, const int* in_sizes, int n_in,
                              void* d_out, int out_size, void* d_ws, size_t ws_size,
                              hipStream_t stream)
{
    const float* data    = (const float*)d_in[0];
    const int*   src     = (const int*)  d_in[1];
    const int*   tgt     = (const int*)  d_in[2];
    const float* W_pre   = (const float*)d_in[3];
    const float* b_pre   = (const float*)d_in[4];
    const float* T_pre   = (const float*)d_in[5];
    const float* bT_pre  = (const float*)d_in[6];
    const float* W_blk   = (const float*)d_in[7];
    const float* b_blk   = (const float*)d_in[8];   // cancels in Lap — unused
    const float* T_blk   = (const float*)d_in[9];
    const float* bT_blk  = (const float*)d_in[10];
    const float* W_post  = (const float*)d_in[11];
    const float* b_post  = (const float*)d_in[12];  // cancels in Lap — unused
    const float* T_post  = (const float*)d_in[13];
    const float* bT_post = (const float*)d_in[14];
    float* out = (float*)d_out;

    float* ws = (float*)d_ws;
    float*   P       = ws;                                   // N*512 f32
    float*   bcat    = P + (size_t)N_NODES * PCOLS;          // 512
    float2*  Wp2     = (float2*)(bcat + 512);                // 3*16*64 float2
    int*     row_ptr = (int*)(Wp2 + 3*16*64);                // 50008
    int*     srcp    = row_ptr + 50008;                      // N*64
    ushortT* Y0b     = (ushortT*)(srcp + (size_t)N_NODES*64);   // (N+1)*96 bf16
    ushortT* rb1     = Y0b + (size_t)(N_NODES+1) * 96;          // (N+1)*96 bf16
    ushortT* rb2     = rb1 + (size_t)(N_NODES+1) * 96;          // (N+1)*96 bf16
    ushortT* Ab      = rb2 + (size_t)(N_NODES+1) * 96;          // N*128 bf16
    ushortT* Wb      = Ab  + (size_t)N_NODES * IN_F;            // 512*128 bf16

    pack_weights<<<(IN_F*PCOLS + 255)/256, 256, 0, stream>>>(
        W_pre, b_pre, T_pre, bT_pre, T_blk, bT_blk, T_post, bT_post,
        W_post, Wb, bcat, Wp2);

    convert_data<<<(N_NODES*IN_F/8 + 255)/256, 256, 0, stream>>>(data, Ab);

    build_row_ptr<<<(N_NODES + 1 + 255)/256, 256, 0, stream>>>(tgt, row_ptr, E_EDGES, N_NODES + 1);

    build_srcp<<<(N_NODES*64)/256, 256, 0, stream>>>(src, row_ptr, srcp, Y0b, rb1, rb2);

    dim3 gg(PCOLS/128, (N_NODES + 127)/128);
    gemm_mfma<<<gg, 256, 0, stream>>>(Ab, Wb, bcat, P, Y0b, N_NODES);

    lap1<<<(N_NODES + 3)/4, 256, 0, stream>>>(Y0b, P, P + 96, srcp, src, row_ptr, rb1);
    lap2<<<N_NODES/CPB, 256, 0, stream>>>(rb1, P + 192, srcp, src, row_ptr, W_blk, rb2);
    lap3<<<N_NODES/CPB, 256, 0, stream>>>(rb2, P + 288, srcp, src, row_ptr, Wp2, out);
}